// Round 1
// baseline (760.508 us; speedup 1.0000x reference)
//
#include <hip/hip_runtime.h>

#define NB 8
#define NT 400
#define NN 200
#define ND 80

static __device__ __forceinline__ float laddexp(float a, float b) {
    float mx = fmaxf(a, b);
    return mx + log1pf(__expf(fminf(a, b) - mx));
}

static constexpr float BIG_NEG = -1e30f;
static constexpr float HALF_LOG2PI = 0.9189385332046727f;  // 0.5*log(2*pi)
static constexpr float LOGEPS = -69.07755278982137f;       // log(1e-30)

// ---------------------------------------------------------------------------
// Kernel 1: emission[b][t][n] = sum_d -0.5*z^2 - log(std) - 0.5*log(2pi)
// 4 lanes per (b,t,n) row, float4 loads, quad shuffle-reduce.
// Rows with t >= mel_lens[b] or n >= inputs_len[b] are skipped (never read).
// ---------------------------------------------------------------------------
__global__ __launch_bounds__(256) void emission_kernel(
    const float* __restrict__ mels,   // (B,T,D)
    const float* __restrict__ means,  // (B,T,N,D)
    const float* __restrict__ stds,   // (B,T,N,D)
    const int* __restrict__ inputs_len,
    const int* __restrict__ mel_lens,
    float* __restrict__ emiss)        // (B,T,N) workspace
{
    const int tid = threadIdx.x;
    const int R = blockIdx.x * 64 + (tid >> 2);  // global row in [0, B*T*N)
    const int q = tid & 3;
    const int b = R / (NT * NN);
    const int r2 = R - b * (NT * NN);
    const int t = r2 / NN;
    const int n = r2 - t * NN;

    if (t >= mel_lens[b] || n >= inputs_len[b]) return;  // never consumed

    const float4* mp = reinterpret_cast<const float4*>(means) + (size_t)R * (ND / 4) + q;
    const float4* sp = reinterpret_cast<const float4*>(stds)  + (size_t)R * (ND / 4) + q;
    const float4* xp = reinterpret_cast<const float4*>(mels)  + (size_t)(b * NT + t) * (ND / 4) + q;

    float acc = 0.f;
#pragma unroll
    for (int k = 0; k < ND / 16; ++k) {
        const float4 m = mp[k * 4];
        const float4 s = sp[k * 4];
        const float4 x = xp[k * 4];
        float z0 = __fdividef(x.x - m.x, s.x);
        float z1 = __fdividef(x.y - m.y, s.y);
        float z2 = __fdividef(x.z - m.z, s.z);
        float z3 = __fdividef(x.w - m.w, s.w);
        acc -= 0.5f * z0 * z0 + __logf(s.x);
        acc -= 0.5f * z1 * z1 + __logf(s.y);
        acc -= 0.5f * z2 * z2 + __logf(s.z);
        acc -= 0.5f * z3 * z3 + __logf(s.w);
    }
    // quad reduce (xor 1,2 stay within the 4-lane group)
    acc += __shfl_xor(acc, 1);
    acc += __shfl_xor(acc, 2);
    if (q == 0) emiss[R] = acc - HALF_LOG2PI * (float)ND;
}

// ---------------------------------------------------------------------------
// Kernel 2: sequential forward recursion, UNNORMALIZED.
// Identity: la_unnorm(t) = la_norm(t) + sum_{s<=t} c_s, so
//   out[b] = la_unnorm[mel_lens-1][inputs_len-1] + log(sigmoid(tv_last)).
// One wave per b; lane l holds states 4l..4l+3; one shfl_up per step.
// ---------------------------------------------------------------------------
__global__ __launch_bounds__(64) void scan_kernel(
    const float* __restrict__ emiss,  // (B,T,N)
    const float* __restrict__ tv,     // (B,T,N)
    const int* __restrict__ inputs_len,
    const int* __restrict__ mel_lens,
    float* __restrict__ out)          // (B,)
{
    const int b = blockIdx.x;
    const int lane = threadIdx.x;
    const int il = inputs_len[b];
    const int ml = mel_lens[b];
    const int n0 = lane * 4;
    const int cl = (lane < NN / 4) ? lane : (NN / 4 - 1);  // clamp: keep loads in-bounds

    const float* eb = emiss + (size_t)b * NT * NN;
    const float* vb = tv    + (size_t)b * NT * NN;

    // t = 0: la = log_priors + emission (only state 0 is finite)
    float la0 = BIG_NEG, la1 = BIG_NEG, la2 = BIG_NEG, la3 = BIG_NEG;
    if (lane == 0) la0 = eb[0];

    // prefetch t = 1
    float4 ecur = reinterpret_cast<const float4*>(eb + NN)[cl];
    float4 vcur = reinterpret_cast<const float4*>(vb + NN)[cl];

    float s0, s1, s2, s3, m0, m1, m2, m3;
    auto softpair = [](float v, float& stay, float& mv) {
        float l1 = log1pf(__expf(-fabsf(v)));
        stay = fmaxf(-(fmaxf(v, 0.f) + l1), LOGEPS);   // log(sigmoid(-v))
        mv   = fmaxf(-(fmaxf(-v, 0.f) + l1), LOGEPS);  // log(sigmoid(v))
    };
    softpair(vcur.x, s0, m0);
    softpair(vcur.y, s1, m1);
    softpair(vcur.z, s2, m2);
    softpair(vcur.w, s3, m3);

    for (int t = 1; t < ml; ++t) {
        // prefetch t+1 (clamped on last iter; always in-bounds and written)
        const int tn = (t + 1 < ml) ? (t + 1) : t;
        float4 enx = reinterpret_cast<const float4*>(eb + (size_t)tn * NN)[cl];
        float4 vnx = reinterpret_cast<const float4*>(vb + (size_t)tn * NN)[cl];

        // neighbor contribution: la_prev[4l-1] + log_move[4l-1] from lane l-1
        float carry = __shfl_up(la3 + m3, 1);
        if (lane == 0) carry = BIG_NEG;

        float st0 = la0 + s0, lv0 = carry;
        float st1 = la1 + s1, lv1 = la0 + m0;
        float st2 = la2 + s2, lv2 = la1 + m1;
        float st3 = la3 + s3, lv3 = la2 + m2;

        la0 = (n0 + 0 < il) ? ecur.x + laddexp(st0, lv0) : BIG_NEG;
        la1 = (n0 + 1 < il) ? ecur.y + laddexp(st1, lv1) : BIG_NEG;
        la2 = (n0 + 2 < il) ? ecur.z + laddexp(st2, lv2) : BIG_NEG;
        la3 = (n0 + 3 < il) ? ecur.w + laddexp(st3, lv3) : BIG_NEG;

        ecur = enx;
        vcur = vnx;
        softpair(vcur.x, s0, m0);
        softpair(vcur.y, s1, m1);
        softpair(vcur.z, s2, m2);
        softpair(vcur.w, s3, m3);
    }

    // final: only state inputs_len-1 contributes (log_trans = BIG_NEG elsewhere)
    const int fin = il - 1;
    if (fin >= n0 && fin < n0 + 4) {
        float tvl = vb[(size_t)(ml - 1) * NN + fin];
        float l1 = log1pf(__expf(-fabsf(tvl)));
        float lmove = fmaxf(-(fmaxf(-tvl, 0.f) + l1), LOGEPS);  // log(sigmoid(tv))
        float lastla = (fin == n0)     ? la0
                     : (fin == n0 + 1) ? la1
                     : (fin == n0 + 2) ? la2
                                       : la3;
        out[b] = lastla + lmove;
    }
}

extern "C" void kernel_launch(void* const* d_in, const int* in_sizes, int n_in,
                              void* d_out, int out_size, void* d_ws, size_t ws_size,
                              hipStream_t stream) {
    const float* mels  = (const float*)d_in[0];
    const float* means = (const float*)d_in[1];
    const float* stds  = (const float*)d_in[2];
    const float* tv    = (const float*)d_in[3];
    const int* inputs_len = (const int*)d_in[4];
    const int* mel_lens   = (const int*)d_in[5];
    float* out = (float*)d_out;
    float* emiss = (float*)d_ws;  // B*T*N floats = 2.56 MB

    const int rows = NB * NT * NN;             // 640000
    emission_kernel<<<dim3(rows / 64), dim3(256), 0, stream>>>(
        mels, means, stds, inputs_len, mel_lens, emiss);
    scan_kernel<<<dim3(NB), dim3(64), 0, stream>>>(
        emiss, tv, inputs_len, mel_lens, out);
}

// Round 3
// 103.635 us; speedup vs baseline: 7.3383x; 7.3383x over previous
//
#include <hip/hip_runtime.h>

#define NB 8
#define NT 400
#define NN 200
#define ND 80

static constexpr float BIG_NEG = -1e30f;
static constexpr float HALF_LOG2PI = 0.9189385332046727f;  // 0.5*log(2*pi)
static constexpr float LOGEPS = -69.07755278982137f;       // log(1e-30)
static constexpr float LN2 = 0.6931471805599453f;
static constexpr float LOG2E = 1.4426950408889634f;

// hardware transcendentals: v_exp_f32 (2^x), v_log_f32 (log2 x)
static __device__ __forceinline__ float hw_exp2(float x) { return __builtin_amdgcn_exp2f(x); }
static __device__ __forceinline__ float hw_log2(float x) { return __builtin_amdgcn_logf(x); }

// log(exp(a)+exp(b)) via hardware exp2/log2 (a,b finite, possibly ~ -1e30)
static __device__ __forceinline__ float laddexp(float a, float b) {
    float mx = fmaxf(a, b);
    float d = fminf(a, b) - mx;  // <= 0
    return mx + LN2 * hw_log2(1.0f + hw_exp2(d * LOG2E));
}

// softplus(-|v|) = log(1+exp(-|v|)), in [0, log2]
static __device__ __forceinline__ float softplus_neg_abs(float v) {
    return LN2 * hw_log2(1.0f + hw_exp2(-fabsf(v) * LOG2E));
}

// ---------------------------------------------------------------------------
// Kernel 1: per (b,t,n) row compute emission e = sum_d -0.5*z^2 - log(std)
// - 0.5*D*log(2pi), then fold the transition terms:
//   SE[t][n] = e + log(sigmoid(-tv[t][n]))        (stay path)
//   ME[t][n] = e + log(sigmoid( tv[t][n-1]))      (move path, pre-shifted)
// Masked states (n >= inputs_len) get SE=ME=BIG_NEG so the scan needs no
// selects. t==0 stores raw e in SE (scan init uses SE[b][0][0] only).
// Rows with t >= mel_lens are never read -> skipped entirely.
// ---------------------------------------------------------------------------
__global__ __launch_bounds__(256) void emission_kernel(
    const float* __restrict__ mels,   // (B,T,D)
    const float* __restrict__ means,  // (B,T,N,D)
    const float* __restrict__ stds,   // (B,T,N,D)
    const float* __restrict__ tv,     // (B,T,N)
    const int* __restrict__ inputs_len,
    const int* __restrict__ mel_lens,
    float* __restrict__ SE,           // (B,T,N) workspace
    float* __restrict__ ME)           // (B,T,N) workspace
{
    const int tid = threadIdx.x;
    const int R = blockIdx.x * 64 + (tid >> 2);  // global row in [0, B*T*N)
    const int q = tid & 3;
    const int b = R / (NT * NN);
    const int r2 = R - b * (NT * NN);
    const int t = r2 / NN;
    const int n = r2 - t * NN;

    if (t >= mel_lens[b]) return;               // never consumed
    if (n >= inputs_len[b]) {                   // masked state: force BIG_NEG
        if (q == 0) { SE[R] = BIG_NEG; ME[R] = BIG_NEG; }
        return;
    }

    const float4* mp = reinterpret_cast<const float4*>(means) + (size_t)R * (ND / 4) + q;
    const float4* sp = reinterpret_cast<const float4*>(stds)  + (size_t)R * (ND / 4) + q;
    const float4* xp = reinterpret_cast<const float4*>(mels)  + (size_t)(b * NT + t) * (ND / 4) + q;

    float acc = 0.f;
#pragma unroll
    for (int k = 0; k < ND / 16; ++k) {
        const float4 m = mp[k * 4];
        const float4 s = sp[k * 4];
        const float4 x = xp[k * 4];
        float z0 = __fdividef(x.x - m.x, s.x);
        float z1 = __fdividef(x.y - m.y, s.y);
        float z2 = __fdividef(x.z - m.z, s.z);
        float z3 = __fdividef(x.w - m.w, s.w);
        acc -= 0.5f * z0 * z0 + __logf(s.x);
        acc -= 0.5f * z1 * z1 + __logf(s.y);
        acc -= 0.5f * z2 * z2 + __logf(s.z);
        acc -= 0.5f * z3 * z3 + __logf(s.w);
    }
    acc += __shfl_xor(acc, 1);
    acc += __shfl_xor(acc, 2);

    if (q == 0) {
        const float e = acc - HALF_LOG2PI * (float)ND;
        if (t == 0) {
            SE[R] = e;           // raw emission; only n==0 consumed at init
            ME[R] = BIG_NEG;
        } else {
            const size_t base = (size_t)b * NT * NN + (size_t)t * NN;
            float v = tv[base + n];
            float spn = softplus_neg_abs(v);
            float stay = -((v > 0.f) ? (v + spn) : spn);       // log sigmoid(-v)
            SE[R] = e + fmaxf(stay, LOGEPS);
            if (n == 0) {
                ME[R] = BIG_NEG;                               // no move into state 0
            } else {
                float u = tv[base + n - 1];
                float spn2 = softplus_neg_abs(u);
                float mv = -((u < 0.f) ? (-u + spn2) : spn2);  // log sigmoid(u)
                ME[R] = e + fmaxf(mv, LOGEPS);
            }
        }
    }
}

// ---------------------------------------------------------------------------
// Kernel 2: unnormalized forward recursion.
//   la[n] <- laddexp(la[n] + SE[t][n], la[n-1] + ME[t][n])
// One wave per b; lane l holds states 4l..4l+3; one shfl_up per step.
// Prefetch depth 4, statically indexed (x4 unroll) to stay in registers.
// out[b] = la[mel_lens-1][inputs_len-1] + log(sigmoid(tv[mel_lens-1][il-1]))
// ---------------------------------------------------------------------------
__global__ __launch_bounds__(64) void scan_kernel(
    const float* __restrict__ SE,     // (B,T,N)
    const float* __restrict__ ME,     // (B,T,N)
    const float* __restrict__ tv,     // (B,T,N)
    const int* __restrict__ inputs_len,
    const int* __restrict__ mel_lens,
    float* __restrict__ out)          // (B,)
{
    const int b = blockIdx.x;
    const int lane = threadIdx.x;
    const int il = inputs_len[b];
    const int ml = mel_lens[b];
    const int cl = (lane < NN / 4) ? lane : (NN / 4 - 1);  // clamp: loads in-bounds

    const float* seb = SE + (size_t)b * NT * NN;
    const float* meb = ME + (size_t)b * NT * NN;
    const float* vb  = tv + (size_t)b * NT * NN;

    // t = 0: only state 0 finite (prior), SE[b][0][0] holds raw emission
    float la0 = (lane == 0) ? seb[0] : BIG_NEG;
    float la1 = BIG_NEG, la2 = BIG_NEG, la3 = BIG_NEG;

    // preload slots for t=1..4 (slot = t & 3)
    auto ld4 = [cl](const float* p) { return reinterpret_cast<const float4*>(p)[cl]; };
    const int mlm1 = ml - 1;
    float4 se1 = ld4(seb + (size_t)((1 <= mlm1) ? 1 : mlm1) * NN);
    float4 me1 = ld4(meb + (size_t)((1 <= mlm1) ? 1 : mlm1) * NN);
    float4 se2 = ld4(seb + (size_t)((2 <= mlm1) ? 2 : mlm1) * NN);
    float4 me2 = ld4(meb + (size_t)((2 <= mlm1) ? 2 : mlm1) * NN);
    float4 se3 = ld4(seb + (size_t)((3 <= mlm1) ? 3 : mlm1) * NN);
    float4 me3 = ld4(meb + (size_t)((3 <= mlm1) ? 3 : mlm1) * NN);
    float4 se0 = ld4(seb + (size_t)((4 <= mlm1) ? 4 : mlm1) * NN);
    float4 me0 = ld4(meb + (size_t)((4 <= mlm1) ? 4 : mlm1) * NN);

#define STEP(S, TT)                                                         \
    {                                                                       \
        float carry = __shfl_up(la3, 1);                                    \
        float a0 = la0 + se##S.x, c0 = carry + me##S.x;                     \
        float a1 = la1 + se##S.y, c1 = la0 + me##S.y;                       \
        float a2 = la2 + se##S.z, c2 = la1 + me##S.z;                       \
        float a3 = la3 + se##S.w, c3 = la2 + me##S.w;                       \
        int tn = ((TT) + 4 <= mlm1) ? ((TT) + 4) : mlm1;                    \
        se##S = ld4(seb + (size_t)tn * NN);                                 \
        me##S = ld4(meb + (size_t)tn * NN);                                 \
        la0 = laddexp(a0, c0);                                              \
        la1 = laddexp(a1, c1);                                              \
        la2 = laddexp(a2, c2);                                              \
        la3 = laddexp(a3, c3);                                              \
    }

    int t = 1;
    for (; t + 3 < ml; t += 4) {
        STEP(1, t)
        STEP(2, t + 1)
        STEP(3, t + 2)
        STEP(0, t + 3)
    }
    // tail (<= 3 iters), direct loads
    for (; t < ml; ++t) {
        float4 se = ld4(seb + (size_t)t * NN);
        float4 me = ld4(meb + (size_t)t * NN);
        float carry = __shfl_up(la3, 1);
        float a0 = la0 + se.x, c0 = carry + me.x;
        float a1 = la1 + se.y, c1 = la0 + me.y;
        float a2 = la2 + se.z, c2 = la1 + me.z;
        float a3 = la3 + se.w, c3 = la2 + me.w;
        la0 = laddexp(a0, c0);
        la1 = laddexp(a1, c1);
        la2 = laddexp(a2, c2);
        la3 = laddexp(a3, c3);
    }
#undef STEP

    // final: only state il-1 contributes
    const int fin = il - 1;
    const int n0 = lane * 4;
    if (fin >= n0 && fin < n0 + 4) {
        float tvl = vb[(size_t)mlm1 * NN + fin];
        float spn = softplus_neg_abs(tvl);
        float lmove = fmaxf(-((tvl < 0.f) ? (-tvl + spn) : spn), LOGEPS);  // log sigmoid(tv)
        float lastla = (fin == n0)     ? la0
                     : (fin == n0 + 1) ? la1
                     : (fin == n0 + 2) ? la2
                                       : la3;
        out[b] = lastla + lmove;
    }
}

extern "C" void kernel_launch(void* const* d_in, const int* in_sizes, int n_in,
                              void* d_out, int out_size, void* d_ws, size_t ws_size,
                              hipStream_t stream) {
    const float* mels  = (const float*)d_in[0];
    const float* means = (const float*)d_in[1];
    const float* stds  = (const float*)d_in[2];
    const float* tv    = (const float*)d_in[3];
    const int* inputs_len = (const int*)d_in[4];
    const int* mel_lens   = (const int*)d_in[5];
    float* out = (float*)d_out;

    float* SE = (float*)d_ws;                    // B*T*N floats = 2.56 MB
    float* ME = SE + (size_t)NB * NT * NN;       // B*T*N floats = 2.56 MB

    const int rows = NB * NT * NN;               // 640000
    emission_kernel<<<dim3(rows / 64), dim3(256), 0, stream>>>(
        mels, means, stds, tv, inputs_len, mel_lens, SE, ME);
    scan_kernel<<<dim3(NB), dim3(64), 0, stream>>>(
        SE, ME, tv, inputs_len, mel_lens, out);
}

// Round 4
// 86.424 us; speedup vs baseline: 8.7997x; 1.1991x over previous
//
#include <hip/hip_runtime.h>

#define NB 8
#define NT 400
#define NN 200
#define ND 80

static constexpr float BIG_NEG = -1e30f;
static constexpr float LN2 = 0.6931471805599453f;
static constexpr float LOG2E = 1.4426950408889634f;
// log2-domain constants
static constexpr float L2EPS = -99.65784284662087f;          // log(1e-30)*LOG2E
static constexpr float HALF_LOG2E = 0.7213475204444817f;     // 0.5*LOG2E
static constexpr float D_HALF_L2PI = 106.05984517680935f;    // D*0.5*log(2pi)*LOG2E

// hardware transcendentals: v_exp_f32 (2^x), v_log_f32 (log2 x)
static __device__ __forceinline__ float hw_exp2(float x) { return __builtin_amdgcn_exp2f(x); }
static __device__ __forceinline__ float hw_log2(float x) { return __builtin_amdgcn_logf(x); }

// log2(2^a + 2^b); a,b possibly ~ -1e30
static __device__ __forceinline__ float l2add(float a, float b) {
    float mx = fmaxf(a, b);
    float d = fminf(a, b) - mx;  // <= 0
    return mx + hw_log2(1.0f + hw_exp2(d));
}

// log2(1 + 2^-|w|), in [0,1]
static __device__ __forceinline__ float softplus2(float w) {
    return hw_log2(1.0f + hw_exp2(-fabsf(w)));
}

// whole-wave shift right by 1 lane via DPP; lane 0 receives `fill`
static __device__ __forceinline__ float wave_shr1(float x, float fill) {
    int r = __builtin_amdgcn_update_dpp(__float_as_int(fill), __float_as_int(x),
                                        0x138 /*wave_shr:1*/, 0xF, 0xF, false);
    return __int_as_float(r);
}

// ---------------------------------------------------------------------------
// Kernel 1 (log2 domain): e2 = LOG2E * emission.
//   SE[t][n] = e2 + log2(sigmoid(-tv[t][n]))      (stay)
//   ME[t][n] = e2 + log2(sigmoid( tv[t][n-1]))    (move, pre-shifted)
// Masked states get BIG_NEG. t==0 stores raw e2 in SE.
// Rows with t >= mel_lens are never read -> skipped.
// ---------------------------------------------------------------------------
__global__ __launch_bounds__(256) void emission_kernel(
    const float* __restrict__ mels,   // (B,T,D)
    const float* __restrict__ means,  // (B,T,N,D)
    const float* __restrict__ stds,   // (B,T,N,D)
    const float* __restrict__ tv,     // (B,T,N)
    const int* __restrict__ inputs_len,
    const int* __restrict__ mel_lens,
    float* __restrict__ SE,           // (B,T,N) workspace
    float* __restrict__ ME)           // (B,T,N) workspace
{
    const int tid = threadIdx.x;
    const int R = blockIdx.x * 64 + (tid >> 2);  // row in [0, B*T*N)
    const int q = tid & 3;
    const int b = R / (NT * NN);
    const int r2 = R - b * (NT * NN);
    const int t = r2 / NN;
    const int n = r2 - t * NN;

    if (t >= mel_lens[b]) return;
    if (n >= inputs_len[b]) {
        if (q == 0) { SE[R] = BIG_NEG; ME[R] = BIG_NEG; }
        return;
    }

    const float4* mp = reinterpret_cast<const float4*>(means) + (size_t)R * (ND / 4) + q;
    const float4* sp = reinterpret_cast<const float4*>(stds)  + (size_t)R * (ND / 4) + q;
    const float4* xp = reinterpret_cast<const float4*>(mels)  + (size_t)(b * NT + t) * (ND / 4) + q;

    // acc = sum( HALF_LOG2E*z^2 + log2(s) );  e2 = -acc - D_HALF_L2PI
    float acc = 0.f;
#pragma unroll
    for (int k = 0; k < ND / 16; ++k) {
        const float4 m = mp[k * 4];
        const float4 s = sp[k * 4];
        const float4 x = xp[k * 4];
        float z0 = __fdividef(x.x - m.x, s.x);
        float z1 = __fdividef(x.y - m.y, s.y);
        float z2 = __fdividef(x.z - m.z, s.z);
        float z3 = __fdividef(x.w - m.w, s.w);
        acc += fmaf(z0 * HALF_LOG2E, z0, hw_log2(s.x));
        acc += fmaf(z1 * HALF_LOG2E, z1, hw_log2(s.y));
        acc += fmaf(z2 * HALF_LOG2E, z2, hw_log2(s.z));
        acc += fmaf(z3 * HALF_LOG2E, z3, hw_log2(s.w));
    }
    acc += __shfl_xor(acc, 1);
    acc += __shfl_xor(acc, 2);

    if (q == 0) {
        const float e2 = -acc - D_HALF_L2PI;
        if (t == 0) {
            SE[R] = e2;          // raw (log2-scaled) emission; only n==0 used
            ME[R] = BIG_NEG;
        } else {
            const size_t base = (size_t)b * NT * NN + (size_t)t * NN;
            float w = tv[base + n] * LOG2E;
            float stay2 = -(fmaxf(w, 0.f) + softplus2(w));     // log2 sigmoid(-v)
            SE[R] = e2 + fmaxf(stay2, L2EPS);
            if (n == 0) {
                ME[R] = BIG_NEG;
            } else {
                float u = tv[base + n - 1] * LOG2E;
                float mv2 = -(fmaxf(-u, 0.f) + softplus2(u));  // log2 sigmoid(v)
                ME[R] = e2 + fmaxf(mv2, L2EPS);
            }
        }
    }
}

// ---------------------------------------------------------------------------
// Kernel 2: unnormalized forward recursion in log2 domain.
//   la[n] <- l2add(la[n] + SE[t][n], la[n-1] + ME[t][n])
// One wave per b; lane l holds states 4l..4l+3; DPP wave_shr for the carry.
// Prefetch depth 8, statically indexed (8-way unroll).
// ---------------------------------------------------------------------------
__global__ __launch_bounds__(64) void scan_kernel(
    const float* __restrict__ SE,     // (B,T,N)
    const float* __restrict__ ME,     // (B,T,N)
    const float* __restrict__ tv,     // (B,T,N)
    const int* __restrict__ inputs_len,
    const int* __restrict__ mel_lens,
    float* __restrict__ out)          // (B,)
{
    const int b = blockIdx.x;
    const int lane = threadIdx.x;
    const int il = inputs_len[b];
    const int ml = mel_lens[b];
    const int cl = (lane < NN / 4) ? lane : (NN / 4 - 1);  // clamp: loads in-bounds

    const float* seb = SE + (size_t)b * NT * NN;
    const float* meb = ME + (size_t)b * NT * NN;
    const float* vb  = tv + (size_t)b * NT * NN;

    float la0 = (lane == 0) ? seb[0] : BIG_NEG;
    float la1 = BIG_NEG, la2 = BIG_NEG, la3 = BIG_NEG;

    auto ld4 = [cl](const float* p) { return reinterpret_cast<const float4*>(p)[cl]; };
    const int mlm1 = ml - 1;
#define PRELOAD(S, TT)                                                      \
    float4 se##S = ld4(seb + (size_t)(((TT) <= mlm1) ? (TT) : mlm1) * NN);  \
    float4 me##S = ld4(meb + (size_t)(((TT) <= mlm1) ? (TT) : mlm1) * NN);
    PRELOAD(1, 1) PRELOAD(2, 2) PRELOAD(3, 3) PRELOAD(4, 4)
    PRELOAD(5, 5) PRELOAD(6, 6) PRELOAD(7, 7) PRELOAD(0, 8)
#undef PRELOAD

#define STEP(S, TT)                                                         \
    {                                                                       \
        float carry = wave_shr1(la3, BIG_NEG);                              \
        float a0 = la0 + se##S.x, c0 = carry + me##S.x;                     \
        float a1 = la1 + se##S.y, c1 = la0 + me##S.y;                       \
        float a2 = la2 + se##S.z, c2 = la1 + me##S.z;                       \
        float a3 = la3 + se##S.w, c3 = la2 + me##S.w;                       \
        int tn = ((TT) + 8 <= mlm1) ? ((TT) + 8) : mlm1;                    \
        se##S = ld4(seb + (size_t)tn * NN);                                 \
        me##S = ld4(meb + (size_t)tn * NN);                                 \
        la0 = l2add(a0, c0);                                                \
        la1 = l2add(a1, c1);                                                \
        la2 = l2add(a2, c2);                                                \
        la3 = l2add(a3, c3);                                                \
    }

    int t = 1;
    for (; t + 7 < ml; t += 8) {
        STEP(1, t)     STEP(2, t + 1) STEP(3, t + 2) STEP(4, t + 3)
        STEP(5, t + 4) STEP(6, t + 5) STEP(7, t + 6) STEP(0, t + 7)
    }
#undef STEP
    // tail (<= 7 iters), direct loads
    for (; t < ml; ++t) {
        float4 se = ld4(seb + (size_t)t * NN);
        float4 me = ld4(meb + (size_t)t * NN);
        float carry = wave_shr1(la3, BIG_NEG);
        float a0 = la0 + se.x, c0 = carry + me.x;
        float a1 = la1 + se.y, c1 = la0 + me.y;
        float a2 = la2 + se.z, c2 = la1 + me.z;
        float a3 = la3 + se.w, c3 = la2 + me.w;
        la0 = l2add(a0, c0);
        la1 = l2add(a1, c1);
        la2 = l2add(a2, c2);
        la3 = l2add(a3, c3);
    }

    // final: only state il-1 contributes; out = LN2 * (la + log2 sigmoid(tv))
    const int fin = il - 1;
    const int n0 = lane * 4;
    if (fin >= n0 && fin < n0 + 4) {
        float w = vb[(size_t)mlm1 * NN + fin] * LOG2E;
        float lmove2 = fmaxf(-(fmaxf(-w, 0.f) + softplus2(w)), L2EPS);
        float lastla = (fin == n0)     ? la0
                     : (fin == n0 + 1) ? la1
                     : (fin == n0 + 2) ? la2
                                       : la3;
        out[b] = LN2 * (lastla + lmove2);
    }
}

extern "C" void kernel_launch(void* const* d_in, const int* in_sizes, int n_in,
                              void* d_out, int out_size, void* d_ws, size_t ws_size,
                              hipStream_t stream) {
    const float* mels  = (const float*)d_in[0];
    const float* means = (const float*)d_in[1];
    const float* stds  = (const float*)d_in[2];
    const float* tv    = (const float*)d_in[3];
    const int* inputs_len = (const int*)d_in[4];
    const int* mel_lens   = (const int*)d_in[5];
    float* out = (float*)d_out;

    float* SE = (float*)d_ws;                    // B*T*N floats = 2.56 MB
    float* ME = SE + (size_t)NB * NT * NN;       // B*T*N floats = 2.56 MB

    const int rows = NB * NT * NN;               // 640000
    emission_kernel<<<dim3(rows / 64), dim3(256), 0, stream>>>(
        mels, means, stds, tv, inputs_len, mel_lens, SE, ME);
    scan_kernel<<<dim3(NB), dim3(64), 0, stream>>>(
        SE, ME, tv, inputs_len, mel_lens, out);
}